// Round 6
// baseline (199.223 us; speedup 1.0000x reference)
//
#include <hip/hip_runtime.h>
#include <cmath>

// RetinaNet focal + smooth-L1 loss. Split structure (main + finalize):
// in-kernel device-fence finalize measured +25-30us vs kernel-boundary
// coherence (R3/R4). R6: 64-anchor tiles -> 4796 blocks (18.7/CU, occupancy-
// capped) and only 5 prefetched loads/thread (R5's 20-deep chain at 4.7
// blocks/CU was latency-bound at ~27% occupancy). B=4, C=80 fixed.
#define GT_CAP 64

typedef float fvec4 __attribute__((ext_vector_type(4)));

__global__ __launch_bounds__(256) void retina_main(
    const float* __restrict__ cls_heads,   // (B, N, 80)
    const float* __restrict__ reg_heads,   // (B, N, 4)
    const float* __restrict__ anchors,     // (B, N, 4) — broadcast across B
    const float* __restrict__ annots,      // (B, M, 5)
    float* __restrict__ ws,                // [B] cls, [B] reg, [B] pos
    int N, int M, int B)
{
    const int b  = blockIdx.y;
    const int n0 = blockIdx.x << 6;        // 64 anchors per block
    const int t  = threadIdx.x;

    __shared__ float s_ann[5 * GT_CAP];
    __shared__ float s_lab[64];
    __shared__ float s_red[12];

    const int mm = (M > GT_CAP) ? GT_CAP : M;
    for (int i = t; i < 5 * mm; i += 256)
        s_ann[i] = annots[(size_t)b * 5 * M + i];
    __syncthreads();

    // ---- phase 1: per-anchor assignment (first wave only, 64 anchors) ----
    float reg_acc = 0.0f;
    float pos_cnt = 0.0f;
    float label   = -1.0f;
    if (t < 64) {
        const int n = n0 + t;
        if (n < N) {
            // anchors identical across batch: read plane 0 (cache-served b>0)
            const float4 a = *(const float4*)(anchors + (size_t)n * 4);
            const bool inside = (a.x > 0.0f) && (a.y > 0.0f) &&
                                (a.z < 640.0f) && (a.w < 640.0f);
            if (inside) {
                const float area_a = (a.z - a.x) * (a.w - a.y);
                float best = -3.0e38f;
                int   bi   = 0;
                bool  any  = false;
                for (int m = 0; m < mm; ++m) {
                    const float gx1 = s_ann[m*5+0], gy1 = s_ann[m*5+1];
                    const float gx2 = s_ann[m*5+2], gy2 = s_ann[m*5+3];
                    const float gc  = s_ann[m*5+4];
                    float v = -1.0f;
                    if (gc >= 0.0f) {
                        any = true;
                        const float iw = fmaxf(fminf(a.z, gx2) - fmaxf(a.x, gx1), 0.0f);
                        const float ih = fmaxf(fminf(a.w, gy2) - fmaxf(a.y, gy1), 0.0f);
                        const float inter = iw * ih;
                        v = inter / (area_a + (gx2 - gx1) * (gy2 - gy1) - inter);
                    }
                    if (v > best) { best = v; bi = m; }   // first-max == jnp.argmax
                }
                if (any) {
                    if (best < 0.4f)      label = 0.0f;
                    else if (best > 0.5f) label = s_ann[bi*5+4] + 1.0f;
                }
                if (label > 0.0f) {
                    pos_cnt = 1.0f;
                    const float aw = a.z - a.x, ah = a.w - a.y;
                    const float acx = a.x + 0.5f * aw, acy = a.y + 0.5f * ah;
                    const float gw = fmaxf(s_ann[bi*5+2] - s_ann[bi*5+0], 1.0f);
                    const float gh = fmaxf(s_ann[bi*5+3] - s_ann[bi*5+1], 1.0f);
                    const float gcx = s_ann[bi*5+0] + 0.5f * gw;
                    const float gcy = s_ann[bi*5+1] + 0.5f * gh;
                    const float tx = (gcx - acx) / aw * 10.0f;
                    const float ty = (gcy - acy) / ah * 10.0f;
                    const float tw = __logf(gw / aw) * 5.0f;
                    const float th = __logf(gh / ah) * 5.0f;
                    const float4 r = *(const float4*)(reg_heads + ((size_t)b * N + n) * 4);
                    const float dx[4] = { fabsf(r.x - tx), fabsf(r.y - ty),
                                          fabsf(r.z - tw), fabsf(r.w - th) };
                    #pragma unroll
                    for (int j = 0; j < 4; ++j) {
                        const float x = dx[j];
                        reg_acc += (x < (1.0f / 9.0f)) ? 4.5f * x * x
                                                       : x - (1.0f / 18.0f);
                    }
                }
            }
        }
        s_lab[t] = label;
    }
    const int anyValid = __syncthreads_or((t < 64 && label >= 0.0f) ? 1 : 0);

    // ---- phase 2: focal loss, 64 anchors x 80 classes = 1280 float4s ----
    // 5 iterations/thread, ALL loads prefetched into independent registers
    // before any consumption (5 outstanding vmem ops/wave; no ring indexing
    // for the compiler to defeat). Loads stay exec-mask-conditional.
    float cls_acc = 0.0f;
    if (anyValid) {
        const float* cls_base = cls_heads + ((size_t)b * N + n0) * 80;
        float labb[5];
        fvec4 pb[5];
        #pragma unroll
        for (int k = 0; k < 5; ++k) {
            const int e = t + (k << 8);
            const int a = e / 20;
            const float lab = s_lab[a];
            fvec4 v = {0.5f, 0.5f, 0.5f, 0.5f};
            if (lab >= 0.0f)
                v = *(const fvec4*)(cls_base + 4 * e);
            labb[k] = lab; pb[k] = v;
        }
        #pragma unroll
        for (int k = 0; k < 5; ++k) {
            const int e  = t + (k << 8);
            const int c4 = e - (e / 20) * 20;
            const float lab  = labb[k];
            const fvec4 v    = pb[k];
            const float mask = (lab >= 0.0f) ? 1.0f : 0.0f;
            const float pv[4] = { v.x, v.y, v.z, v.w };
            const float cb = (float)(c4 * 4 + 1);
            float local = 0.0f;
            #pragma unroll
            for (int j = 0; j < 4; ++j) {
                const float p = fminf(fmaxf(pv[j], 1.0e-4f), 1.0f - 1.0e-4f);
                const bool  is_pos = (lab == cb + (float)j);
                const float pt     = is_pos ? p : 1.0f - p;
                const float alpha  = is_pos ? 0.25f : 0.75f;
                const float om     = 1.0f - pt;
                local += alpha * om * om * (-__logf(pt));
            }
            cls_acc += mask * local;
        }
    }

    // ---- block reduction: 3 values over 256 threads ----
    const int lane = t & 63, wid = t >> 6;
    #pragma unroll
    for (int off = 32; off > 0; off >>= 1) {
        cls_acc += __shfl_down(cls_acc, off, 64);
        reg_acc += __shfl_down(reg_acc, off, 64);
        pos_cnt += __shfl_down(pos_cnt, off, 64);
    }
    if (lane == 0) {
        s_red[wid]     = cls_acc;
        s_red[4 + wid] = reg_acc;
        s_red[8 + wid] = pos_cnt;
    }
    __syncthreads();
    if (t == 0) {
        const float c = s_red[0] + s_red[1] + s_red[2]  + s_red[3];
        const float r = s_red[4] + s_red[5] + s_red[6]  + s_red[7];
        const float p = s_red[8] + s_red[9] + s_red[10] + s_red[11];
        if (c != 0.0f) atomicAdd(&ws[b], c);
        if (r != 0.0f) atomicAdd(&ws[B + b], r);
        if (p != 0.0f) atomicAdd(&ws[2 * B + b], p);
    }
}

__global__ void retina_final(const float* __restrict__ ws,
                             float* __restrict__ out, int B)
{
    if (threadIdx.x == 0 && blockIdx.x == 0) {
        float cl = 0.0f, rl = 0.0f, nv = 0.0f;
        for (int b = 0; b < B; ++b) {
            const float pos = ws[2 * B + b];
            if (pos > 0.0f) {
                cl += ws[b]     / fmaxf(pos, 1.0f);
                rl += ws[B + b] / fmaxf(4.0f * pos, 1.0f);
                nv += 1.0f;
            }
        }
        const float n = fmaxf(nv, 1.0f);
        out[0] = cl / n;
        out[1] = rl / n;
    }
}

extern "C" void kernel_launch(void* const* d_in, const int* in_sizes, int n_in,
                              void* d_out, int out_size, void* d_ws, size_t ws_size,
                              hipStream_t stream) {
    const float* cls = (const float*)d_in[0];
    const float* reg = (const float*)d_in[1];
    const float* anc = (const float*)d_in[2];
    const float* ann = (const float*)d_in[3];

    const int B = 4;
    const int N = in_sizes[1] / (4 * B);      // 76725
    const int M = in_sizes[3] / (5 * B);      // 16
    float* ws = (float*)d_ws;

    (void)hipMemsetAsync(d_ws, 0, 12 * sizeof(float), stream);

    dim3 grid((N + 63) / 64, B);              // 1199 x 4 = 4796 blocks
    retina_main<<<grid, 256, 0, stream>>>(cls, reg, anc, ann, ws, N, M, B);
    retina_final<<<1, 64, 0, stream>>>(ws, (float*)d_out, B);
}

// Round 7
// 175.735 us; speedup vs baseline: 1.1337x; 1.1337x over previous
//
#include <hip/hip_runtime.h>
#include <cmath>

// RetinaNet focal + smooth-L1 loss. Split main+finalize (R3/R4: in-kernel
// device-fence finalize costs +25-30us vs kernel-boundary coherence).
// R7: phase-2 cls reads via __builtin_amdgcn_global_load_lds DMA staging —
// R4/R5/R6 proved the compiler serializes VGPR-destination loads (VGPR_Count
// 24-28, one outstanding load/wave); the LDS-DMA path has no VGPR dest and a
// 63-deep HW queue. 128-anchor tile = 40KB LDS -> 3 blocks/CU; single barrier
// placed AFTER phase 1 so DMA flies during IoU/assignment work.
// B=4, C=80 fixed by reference.

typedef float fvec4 __attribute__((ext_vector_type(4)));

__device__ __forceinline__ void async_ld16(const float* g, float* l) {
    __builtin_amdgcn_global_load_lds(
        (const __attribute__((address_space(1))) unsigned int*)g,
        (__attribute__((address_space(3))) unsigned int*)l,
        16, 0, 0);
}

__global__ __launch_bounds__(256) void retina_main(
    const float* __restrict__ cls_heads,   // (B, N, 80)
    const float* __restrict__ reg_heads,   // (B, N, 4)
    const float* __restrict__ anchors,     // (B, N, 4) — broadcast across B
    const float* __restrict__ annots,      // (B, M, 5)
    float* __restrict__ ws,                // [B] cls, [B] reg, [B] pos
    int N, int M, int B)
{
    const int b  = blockIdx.y;
    const int n0 = blockIdx.x << 7;        // 128 anchors per block
    const int t  = threadIdx.x;

    __shared__ float s_cls[128 * 80];      // 40 KB staged class tile
    __shared__ float s_lab[128];
    __shared__ float s_red[12];

    // ---- issue DMA staging FIRST (all 256 lanes active, 10 issues/thread,
    // all outstanding in the HW queue while phase 1 computes) ----
    const int tile   = (N - n0 < 128) ? (N - n0) : 128;
    const int valid4 = tile * 20;          // valid float4 count in this tile
    const float* gbase = cls_heads + ((size_t)b * N + n0) * 80;
    #pragma unroll
    for (int k = 0; k < 10; ++k) {
        const int idx  = (k << 8) + t;               // float4 slot 0..2559
        const int gidx = (idx < valid4) ? idx : 0;   // tail clamp (no OOB)
        async_ld16(gbase + 4 * gidx, &s_cls[4 * idx]);
    }

    // ---- phase 1: per-anchor assignment (threads 0..127), annots straight
    // from global (uniform addresses -> scalar loads, L2-hit) — NO barrier
    // here, so the DMA queue keeps draining underneath ----
    float reg_acc = 0.0f;
    float pos_cnt = 0.0f;
    float label   = -1.0f;
    if (t < 128) {
        const int n = n0 + t;
        if (n < N) {
            // anchors identical across batch: read plane 0 (cache-served b>0)
            const float4 a = *(const float4*)(anchors + (size_t)n * 4);
            const bool inside = (a.x > 0.0f) && (a.y > 0.0f) &&
                                (a.z < 640.0f) && (a.w < 640.0f);
            if (inside) {
                const float* ann = annots + (size_t)b * 5 * M;
                const float area_a = (a.z - a.x) * (a.w - a.y);
                float best = -3.0e38f;
                int   bi   = 0;
                bool  any  = false;
                for (int m = 0; m < M; ++m) {
                    const float gx1 = ann[m*5+0], gy1 = ann[m*5+1];
                    const float gx2 = ann[m*5+2], gy2 = ann[m*5+3];
                    const float gc  = ann[m*5+4];
                    float v = -1.0f;
                    if (gc >= 0.0f) {
                        any = true;
                        const float iw = fmaxf(fminf(a.z, gx2) - fmaxf(a.x, gx1), 0.0f);
                        const float ih = fmaxf(fminf(a.w, gy2) - fmaxf(a.y, gy1), 0.0f);
                        const float inter = iw * ih;
                        v = inter / (area_a + (gx2 - gx1) * (gy2 - gy1) - inter);
                    }
                    if (v > best) { best = v; bi = m; }   // first-max == jnp.argmax
                }
                if (any) {
                    if (best < 0.4f)      label = 0.0f;
                    else if (best > 0.5f) label = ann[bi*5+4] + 1.0f;
                }
                if (label > 0.0f) {
                    pos_cnt = 1.0f;
                    const float aw = a.z - a.x, ah = a.w - a.y;
                    const float acx = a.x + 0.5f * aw, acy = a.y + 0.5f * ah;
                    const float gw = fmaxf(ann[bi*5+2] - ann[bi*5+0], 1.0f);
                    const float gh = fmaxf(ann[bi*5+3] - ann[bi*5+1], 1.0f);
                    const float gcx = ann[bi*5+0] + 0.5f * gw;
                    const float gcy = ann[bi*5+1] + 0.5f * gh;
                    const float tx = (gcx - acx) / aw * 10.0f;
                    const float ty = (gcy - acy) / ah * 10.0f;
                    const float tw = __logf(gw / aw) * 5.0f;
                    const float th = __logf(gh / ah) * 5.0f;
                    const float4 r = *(const float4*)(reg_heads + ((size_t)b * N + n) * 4);
                    const float dx[4] = { fabsf(r.x - tx), fabsf(r.y - ty),
                                          fabsf(r.z - tw), fabsf(r.w - th) };
                    #pragma unroll
                    for (int j = 0; j < 4; ++j) {
                        const float x = dx[j];
                        reg_acc += (x < (1.0f / 9.0f)) ? 4.5f * x * x
                                                       : x - (1.0f / 18.0f);
                    }
                }
            }
        }
        s_lab[t] = label;
    }

    // Single barrier: drains this wave's DMA (explicit waitcnt, belt &
    // suspenders vs barrier codegen) + publishes s_lab + block-wide any().
    __builtin_amdgcn_s_waitcnt(0);
    const int anyValid = __syncthreads_or(label >= 0.0f ? 1 : 0);

    // ---- phase 2: focal loss from LDS (128 anchors x 20 float4 = 2560),
    // 10 chunks/thread, ds_read_b128 throughput-bound + VALU ----
    float cls_acc = 0.0f;
    if (anyValid) {
        #pragma unroll
        for (int k = 0; k < 10; ++k) {
            const int e  = (k << 8) + t;      // 0..2559
            const int a  = e / 20;            // anchor 0..127
            const int c4 = e - a * 20;
            const float lab = s_lab[a];
            if (lab >= 0.0f) {
                const fvec4 v = *(const fvec4*)&s_cls[4 * e];
                const float pv[4] = { v.x, v.y, v.z, v.w };
                const float cb = (float)(c4 * 4 + 1);
                float local = 0.0f;
                #pragma unroll
                for (int j = 0; j < 4; ++j) {
                    const float p = fminf(fmaxf(pv[j], 1.0e-4f), 1.0f - 1.0e-4f);
                    const bool  is_pos = (lab == cb + (float)j);
                    const float pt     = is_pos ? p : 1.0f - p;
                    const float alpha  = is_pos ? 0.25f : 0.75f;
                    const float om     = 1.0f - pt;
                    local += alpha * om * om * (-__logf(pt));
                }
                cls_acc += local;
            }
        }
    }

    // ---- block reduction: 3 values over 256 threads ----
    const int lane = t & 63, wid = t >> 6;
    #pragma unroll
    for (int off = 32; off > 0; off >>= 1) {
        cls_acc += __shfl_down(cls_acc, off, 64);
        reg_acc += __shfl_down(reg_acc, off, 64);
        pos_cnt += __shfl_down(pos_cnt, off, 64);
    }
    if (lane == 0) {
        s_red[wid]     = cls_acc;
        s_red[4 + wid] = reg_acc;
        s_red[8 + wid] = pos_cnt;
    }
    __syncthreads();
    if (t == 0) {
        const float c = s_red[0] + s_red[1] + s_red[2]  + s_red[3];
        const float r = s_red[4] + s_red[5] + s_red[6]  + s_red[7];
        const float p = s_red[8] + s_red[9] + s_red[10] + s_red[11];
        if (c != 0.0f) atomicAdd(&ws[b], c);
        if (r != 0.0f) atomicAdd(&ws[B + b], r);
        if (p != 0.0f) atomicAdd(&ws[2 * B + b], p);
    }
}

__global__ void retina_final(const float* __restrict__ ws,
                             float* __restrict__ out, int B)
{
    if (threadIdx.x == 0 && blockIdx.x == 0) {
        float cl = 0.0f, rl = 0.0f, nv = 0.0f;
        for (int b = 0; b < B; ++b) {
            const float pos = ws[2 * B + b];
            if (pos > 0.0f) {
                cl += ws[b]     / fmaxf(pos, 1.0f);
                rl += ws[B + b] / fmaxf(4.0f * pos, 1.0f);
                nv += 1.0f;
            }
        }
        const float n = fmaxf(nv, 1.0f);
        out[0] = cl / n;
        out[1] = rl / n;
    }
}

extern "C" void kernel_launch(void* const* d_in, const int* in_sizes, int n_in,
                              void* d_out, int out_size, void* d_ws, size_t ws_size,
                              hipStream_t stream) {
    const float* cls = (const float*)d_in[0];
    const float* reg = (const float*)d_in[1];
    const float* anc = (const float*)d_in[2];
    const float* ann = (const float*)d_in[3];

    const int B = 4;
    const int N = in_sizes[1] / (4 * B);      // 76725
    const int M = in_sizes[3] / (5 * B);      // 16
    float* ws = (float*)d_ws;

    (void)hipMemsetAsync(d_ws, 0, 12 * sizeof(float), stream);

    dim3 grid((N + 127) / 128, B);            // 600 x 4 = 2400 blocks
    retina_main<<<grid, 256, 0, stream>>>(cls, reg, anc, ann, ws, N, M, B);
    retina_final<<<1, 64, 0, stream>>>(ws, (float*)d_out, B);
}

// Round 8
// 171.589 us; speedup vs baseline: 1.1610x; 1.0242x over previous
//
#include <hip/hip_runtime.h>
#include <cmath>

// RetinaNet focal + smooth-L1 loss. Split main+finalize (R3/R4: in-kernel
// device-fence finalize costs +25-30us vs kernel-boundary coherence).
// R8: WAVE-SPECIALIZED DMA staging. R7's flaw: vmcnt is per-wave and ordered —
// issuing 10 DMAs then consuming an anchor load forces vmcnt(0), draining all
// DMAs before phase 1 (zero overlap, 58.8us). Fix: waves 2-3 issue ALL the
// global_load_lds staging and no other vmem (their drain is one pipelined
// 20-deep stream at the barrier); waves 0-1 run phase 1 on their own
// independent vmcnt. B=4, C=80 fixed by reference.

typedef float fvec4 __attribute__((ext_vector_type(4)));

__device__ __forceinline__ void async_ld16(const float* g, float* l) {
    __builtin_amdgcn_global_load_lds(
        (const __attribute__((address_space(1))) unsigned int*)g,
        (__attribute__((address_space(3))) unsigned int*)l,
        16, 0, 0);
}

__global__ __launch_bounds__(256) void retina_main(
    const float* __restrict__ cls_heads,   // (B, N, 80)
    const float* __restrict__ reg_heads,   // (B, N, 4)
    const float* __restrict__ anchors,     // (B, N, 4) — broadcast across B
    const float* __restrict__ annots,      // (B, M, 5)
    float* __restrict__ ws,                // [B] cls, [B] reg, [B] pos
    int N, int M, int B)
{
    const int b  = blockIdx.y;
    const int n0 = blockIdx.x << 7;        // 128 anchors per block
    const int t  = threadIdx.x;
    const int wave = t >> 6;

    __shared__ float s_cls[128 * 80];      // 40 KB staged class tile
    __shared__ float s_lab[128];
    __shared__ float s_red[12];

    float reg_acc = 0.0f;
    float pos_cnt = 0.0f;
    float label   = -1.0f;

    if (wave >= 2) {
        // ---- producer waves: 20 DMA issues each (20 KB/wave), NO other
        // vmem -> barrier drain is one pipelined stream on this wave's vmcnt.
        const int tile   = (N - n0 < 128) ? (N - n0) : 128;
        const int valid4 = tile * 20;
        const float* gbase = cls_heads + ((size_t)b * N + n0) * 80;
        const int base = (wave - 2) * 1280 + (t & 63);   // slot for k=0
        #pragma unroll
        for (int k = 0; k < 20; ++k) {
            const int idx  = base + (k << 6);            // wave-uniform + lane
            const int gidx = (idx < valid4) ? idx : 0;   // tail clamp (no OOB)
            async_ld16(gbase + 4 * gidx, &s_cls[4 * idx]);
        }
    } else {
        // ---- consumer waves: phase 1 for 128 anchors on own vmcnt ----
        const int n = n0 + t;
        if (n < N) {
            // anchors identical across batch: read plane 0 (cache-served b>0)
            const float4 a = *(const float4*)(anchors + (size_t)n * 4);
            const bool inside = (a.x > 0.0f) && (a.y > 0.0f) &&
                                (a.z < 640.0f) && (a.w < 640.0f);
            if (inside) {
                const float* ann = annots + (size_t)b * 5 * M;
                const float area_a = (a.z - a.x) * (a.w - a.y);
                float best = -3.0e38f;
                int   bi   = 0;
                bool  any  = false;
                for (int m = 0; m < M; ++m) {
                    const float gx1 = ann[m*5+0], gy1 = ann[m*5+1];
                    const float gx2 = ann[m*5+2], gy2 = ann[m*5+3];
                    const float gc  = ann[m*5+4];
                    float v = -1.0f;
                    if (gc >= 0.0f) {
                        any = true;
                        const float iw = fmaxf(fminf(a.z, gx2) - fmaxf(a.x, gx1), 0.0f);
                        const float ih = fmaxf(fminf(a.w, gy2) - fmaxf(a.y, gy1), 0.0f);
                        const float inter = iw * ih;
                        v = inter / (area_a + (gx2 - gx1) * (gy2 - gy1) - inter);
                    }
                    if (v > best) { best = v; bi = m; }   // first-max == jnp.argmax
                }
                if (any) {
                    if (best < 0.4f)      label = 0.0f;
                    else if (best > 0.5f) label = ann[bi*5+4] + 1.0f;
                }
                if (label > 0.0f) {
                    pos_cnt = 1.0f;
                    const float aw = a.z - a.x, ah = a.w - a.y;
                    const float acx = a.x + 0.5f * aw, acy = a.y + 0.5f * ah;
                    const float gw = fmaxf(ann[bi*5+2] - ann[bi*5+0], 1.0f);
                    const float gh = fmaxf(ann[bi*5+3] - ann[bi*5+1], 1.0f);
                    const float gcx = ann[bi*5+0] + 0.5f * gw;
                    const float gcy = ann[bi*5+1] + 0.5f * gh;
                    const float tx = (gcx - acx) / aw * 10.0f;
                    const float ty = (gcy - acy) / ah * 10.0f;
                    const float tw = __logf(gw / aw) * 5.0f;
                    const float th = __logf(gh / ah) * 5.0f;
                    const float4 r = *(const float4*)(reg_heads + ((size_t)b * N + n) * 4);
                    const float dx[4] = { fabsf(r.x - tx), fabsf(r.y - ty),
                                          fabsf(r.z - tw), fabsf(r.w - th) };
                    #pragma unroll
                    for (int j = 0; j < 4; ++j) {
                        const float x = dx[j];
                        reg_acc += (x < (1.0f / 9.0f)) ? 4.5f * x * x
                                                       : x - (1.0f / 18.0f);
                    }
                }
            }
        }
        s_lab[t] = label;
    }

    // Barrier: drains each wave's own vmcnt (producer waves' DMA stream; the
    // compiler emits the waitcnt) + publishes s_lab + block-wide any().
    const int anyValid = __syncthreads_or(label >= 0.0f ? 1 : 0);

    // ---- phase 2: focal loss from LDS (128 anchors x 20 float4 = 2560),
    // 10 chunks/thread on all 4 waves ----
    float cls_acc = 0.0f;
    if (anyValid) {
        #pragma unroll
        for (int k = 0; k < 10; ++k) {
            const int e  = (k << 8) + t;      // 0..2559
            const int a  = e / 20;            // anchor 0..127
            const int c4 = e - a * 20;
            const float lab = s_lab[a];
            if (lab >= 0.0f) {
                const fvec4 v = *(const fvec4*)&s_cls[4 * e];
                const float pv[4] = { v.x, v.y, v.z, v.w };
                const float cb = (float)(c4 * 4 + 1);
                float local = 0.0f;
                #pragma unroll
                for (int j = 0; j < 4; ++j) {
                    const float p = fminf(fmaxf(pv[j], 1.0e-4f), 1.0f - 1.0e-4f);
                    const bool  is_pos = (lab == cb + (float)j);
                    const float pt     = is_pos ? p : 1.0f - p;
                    const float alpha  = is_pos ? 0.25f : 0.75f;
                    const float om     = 1.0f - pt;
                    local += alpha * om * om * (-__logf(pt));
                }
                cls_acc += local;
            }
        }
    }

    // ---- block reduction: 3 values over 256 threads ----
    const int lane = t & 63, wid = t >> 6;
    #pragma unroll
    for (int off = 32; off > 0; off >>= 1) {
        cls_acc += __shfl_down(cls_acc, off, 64);
        reg_acc += __shfl_down(reg_acc, off, 64);
        pos_cnt += __shfl_down(pos_cnt, off, 64);
    }
    if (lane == 0) {
        s_red[wid]     = cls_acc;
        s_red[4 + wid] = reg_acc;
        s_red[8 + wid] = pos_cnt;
    }
    __syncthreads();
    if (t == 0) {
        const float c = s_red[0] + s_red[1] + s_red[2]  + s_red[3];
        const float r = s_red[4] + s_red[5] + s_red[6]  + s_red[7];
        const float p = s_red[8] + s_red[9] + s_red[10] + s_red[11];
        if (c != 0.0f) atomicAdd(&ws[b], c);
        if (r != 0.0f) atomicAdd(&ws[B + b], r);
        if (p != 0.0f) atomicAdd(&ws[2 * B + b], p);
    }
}

__global__ void retina_final(const float* __restrict__ ws,
                             float* __restrict__ out, int B)
{
    if (threadIdx.x == 0 && blockIdx.x == 0) {
        float cl = 0.0f, rl = 0.0f, nv = 0.0f;
        for (int b = 0; b < B; ++b) {
            const float pos = ws[2 * B + b];
            if (pos > 0.0f) {
                cl += ws[b]     / fmaxf(pos, 1.0f);
                rl += ws[B + b] / fmaxf(4.0f * pos, 1.0f);
                nv += 1.0f;
            }
        }
        const float n = fmaxf(nv, 1.0f);
        out[0] = cl / n;
        out[1] = rl / n;
    }
}

extern "C" void kernel_launch(void* const* d_in, const int* in_sizes, int n_in,
                              void* d_out, int out_size, void* d_ws, size_t ws_size,
                              hipStream_t stream) {
    const float* cls = (const float*)d_in[0];
    const float* reg = (const float*)d_in[1];
    const float* anc = (const float*)d_in[2];
    const float* ann = (const float*)d_in[3];

    const int B = 4;
    const int N = in_sizes[1] / (4 * B);      // 76725
    const int M = in_sizes[3] / (5 * B);      // 16
    float* ws = (float*)d_ws;

    (void)hipMemsetAsync(d_ws, 0, 12 * sizeof(float), stream);

    dim3 grid((N + 127) / 128, B);            // 600 x 4 = 2400 blocks
    retina_main<<<grid, 256, 0, stream>>>(cls, reg, anc, ann, ws, N, M, B);
    retina_final<<<1, 64, 0, stream>>>(ws, (float*)d_out, B);
}